// Round 1
// baseline (22170.433 us; speedup 1.0000x reference)
//
#include <hip/hip_runtime.h>
#include <hip/hip_cooperative_groups.h>

namespace cg = cooperative_groups;

#define TT 512
#define FF 64

typedef __attribute__((ext_vector_type(8))) short short8;
typedef __attribute__((ext_vector_type(4))) float floatx4;

// Split fp32 v into bf16 hi + bf16 lo (residual), packed (hi<<16)|lo.
__device__ __forceinline__ unsigned int split_pack(float v) {
    unsigned int u  = __float_as_uint(v);
    unsigned int hb = u & 0xffff0000u;          // truncated-bf16 hi, exact in fp32
    float r = v - __uint_as_float(hb);          // exact residual
    return hb | (__float_as_uint(r) >> 16);
}

__device__ __forceinline__ float sigmoidf_(float z) {
    return 1.0f / (1.0f + __expf(-z));
}

__device__ __forceinline__ void unpack_pk(const unsigned int* hp, short8& ah, short8& al) {
    uint4 pa = *(const uint4*)(hp);
    uint4 pb = *(const uint4*)(hp + 4);
    unsigned int pv[8] = {pa.x, pa.y, pa.z, pa.w, pb.x, pb.y, pb.z, pb.w};
#pragma unroll
    for (int j = 0; j < 8; ++j) {
        ah[j] = (short)(pv[j] >> 16);
        al[j] = (short)(pv[j] & 0xffffu);
    }
}

__device__ __forceinline__ void cvt_x(const float* xp, short8& ah, short8& al) {
    float4 xa = *(const float4*)(xp);
    float4 xb = *(const float4*)(xp + 4);
    float xv[8] = {xa.x, xa.y, xa.z, xa.w, xb.x, xb.y, xb.z, xb.w};
#pragma unroll
    for (int j = 0; j < 8; ++j) {
        unsigned int u  = __float_as_uint(xv[j]);
        unsigned int hb = u & 0xffff0000u;
        float r = xv[j] - __uint_as_float(hb);
        ah[j] = (short)(u >> 16);
        al[j] = (short)(__float_as_uint(r) >> 16);
    }
}

// One LSTM layer role. Block owns 4 units (16 gate cols) x 32 batch rows.
// A = [x_t | h_prev] (layer1) or [h1_t | h2_prev] (layer2), K = 32*NKC.
// Weights pre-split to bf16 hi/lo MFMA B-fragments held in registers.
// MFMA 16x16x32_bf16 layouts (verified, cdna_hip_programming.md §3):
//   A: m=lane&15, k=quad*8+j ; B: n=lane&15, k=quad*8+j ; D: col=lane&15, row=quad*4+r
template<int NKC, int KX, int GW, int UU, bool L1>
__device__ void lstm_role(const float* __restrict__ x,
                          const float* __restrict__ Wm, const float* __restrict__ Um,
                          const float* __restrict__ bias,
                          unsigned int* __restrict__ h1pk, unsigned int* __restrict__ h2pk,
                          float* __restrict__ out,
                          int u0, int b_base,
                          float (*zex)[17], cg::grid_group& grid)
{
    const int tid  = threadIdx.x;
    const int lane = tid & 63;
    const int wv   = tid >> 6;          // 2 waves: m-tile 0 / 1
    const int n    = lane & 15;         // local gate-col
    const int quad = lane >> 4;
    const int gate = n >> 2;            // i,f,g,o
    const int col  = gate * UU + u0 + (n & 3);

    // ---- one-time: weight B-fragments (hi/lo split), bias ----
    short8 bh[NKC], bl[NKC];
#pragma unroll
    for (int kc = 0; kc < NKC; ++kc) {
#pragma unroll
        for (int j = 0; j < 8; ++j) {
            int k = kc * 32 + quad * 8 + j;
            float w = (k < KX) ? Wm[k * GW + col] : Um[(k - KX) * GW + col];
            unsigned int p = split_pack(w);
            bh[kc][j] = (short)(p >> 16);
            bl[kc][j] = (short)(p & 0xffffu);
        }
    }
    const float bias_v = bias[col];

    // ---- zero the "step -1" h buffer slice this block owns (ws is poisoned) ----
    {
        int b_l = tid & 31, ul = tid >> 5;
        if (L1) h1pk[32768 + (b_base + b_l) * 256 + u0 + ul] = 0u;
        else    h2pk[16384 + (b_base + b_l) * 128 + u0 + ul] = 0u;
    }
    float cstate = 0.0f;                     // cell state for (b_base+(tid&31), u0+(tid>>5))
    const int m_g = b_base + wv * 16 + n;    // global batch row for this lane's A-frag

    grid.sync();

    for (int it = 0; it <= 512; ++it) {
        const bool active = L1 ? (it < 512) : (it >= 1);
        if (active) {
            const int s = L1 ? it : (it - 1);
            floatx4 acc = {bias_v, bias_v, bias_v, bias_v};

            const float* xsrc = nullptr;
            const unsigned int* hA;
            const unsigned int* hB = nullptr;
            if (L1) {
                xsrc = x + m_g * (TT * FF) + s * FF;
                hA = h1pk + ((it + 1) & 1) * 32768 + m_g * 256;   // h1[s-1]
            } else {
                hA = h1pk + (s & 1) * 32768 + m_g * 256;          // h1[s]
                hB = h2pk + ((s + 1) & 1) * 16384 + m_g * 128;    // h2[s-1]
            }
#pragma unroll
            for (int kc = 0; kc < NKC; ++kc) {
                short8 ah, al;
                if (L1) {
                    if (kc < 2) cvt_x(xsrc + kc * 32 + quad * 8, ah, al);
                    else        unpack_pk(hA + kc * 32 - 64 + quad * 8, ah, al);
                } else {
                    if (kc < 8) unpack_pk(hA + kc * 32 + quad * 8, ah, al);
                    else        unpack_pk(hB + (kc - 8) * 32 + quad * 8, ah, al);
                }
                acc = __builtin_amdgcn_mfma_f32_16x16x32_bf16(ah, bh[kc], acc, 0, 0, 0);
                acc = __builtin_amdgcn_mfma_f32_16x16x32_bf16(ah, bl[kc], acc, 0, 0, 0);
                acc = __builtin_amdgcn_mfma_f32_16x16x32_bf16(al, bh[kc], acc, 0, 0, 0);
            }
            // ---- gather the 4 gates per (b,unit) via LDS ----
#pragma unroll
            for (int r = 0; r < 4; ++r) zex[wv * 16 + quad * 4 + r][n] = acc[r];
            __syncthreads();
            {
                int b_l = tid & 31, ul = tid >> 5;
                float zi = zex[b_l][ 0 + ul];
                float zf = zex[b_l][ 4 + ul];
                float zg = zex[b_l][ 8 + ul];
                float zo = zex[b_l][12 + ul];
                float ig = sigmoidf_(zi);
                float fg = sigmoidf_(zf);
                float gg = fmaxf(zg, 0.0f);
                float og = sigmoidf_(zo);
                cstate = fg * cstate + ig * gg;
                float h = og * fmaxf(cstate, 0.0f);
                unsigned int p = split_pack(h);
                int b = b_base + b_l;
                if (L1) {
                    h1pk[(it & 1) * 32768 + b * 256 + u0 + ul] = p;
                } else {
                    h2pk[(s & 1) * 16384 + b * 128 + u0 + ul] = p;
                    if (s == 511) out[b * 128 + u0 + ul] = h;
                }
            }
        }
        grid.sync();   // publishes h slices to all XCDs; also intra-block barrier for zex reuse
    }
}

__global__ void __launch_bounds__(128, 2)
lstm_fused_kernel(const float* __restrict__ x,
                  const float* __restrict__ W1, const float* __restrict__ U1,
                  const float* __restrict__ b1,
                  const float* __restrict__ W2, const float* __restrict__ U2,
                  const float* __restrict__ b2,
                  float* __restrict__ out, unsigned int* __restrict__ ws)
{
    cg::grid_group grid = cg::this_grid();
    __shared__ float zex[32][17];
    unsigned int* h1pk = ws;            // [2][128][256] packed hi/lo bf16
    unsigned int* h2pk = ws + 65536;    // [2][128][128]
    int bid = blockIdx.x;
    if (bid < 256) {
        // layer1: 64 col-groups x 4 batch-quarters
        lstm_role<10, 64, 1024, 256, true >(x, W1, U1, b1, h1pk, h2pk, out,
                                            (bid >> 2) * 4, (bid & 3) * 32, zex, grid);
    } else {
        int b2id = bid - 256;           // layer2: 32 col-groups x 4 batch-quarters
        lstm_role<12, 256, 512, 128, false>(x, W2, U2, b2, h1pk, h2pk, out,
                                            (b2id >> 2) * 4, (b2id & 3) * 32, zex, grid);
    }
}

extern "C" void kernel_launch(void* const* d_in, const int* in_sizes, int n_in,
                              void* d_out, int out_size, void* d_ws, size_t ws_size,
                              hipStream_t stream) {
    const float* x  = (const float*)d_in[0];
    const float* W1 = (const float*)d_in[1];
    const float* U1 = (const float*)d_in[2];
    const float* b1 = (const float*)d_in[3];
    const float* W2 = (const float*)d_in[4];
    const float* U2 = (const float*)d_in[5];
    const float* b2 = (const float*)d_in[6];
    float* out = (float*)d_out;
    unsigned int* ws = (unsigned int*)d_ws;
    void* args[] = {&x, &W1, &U1, &b1, &W2, &U2, &b2, &out, &ws};
    hipLaunchCooperativeKernel((void*)lstm_fused_kernel, dim3(384), dim3(128),
                               args, 0, stream);
}

// Round 5
// 3192.796 us; speedup vs baseline: 6.9439x; 6.9439x over previous
//
#include <hip/hip_runtime.h>

#define NG 8      // independent batch groups (16 rows each)
#define GB 12u    // blocks per group: 8 layer1 + 4 layer2

// One monotonic barrier counter per group, 128 B apart. Zeroed by init_kernel
// (stream-ordered before the main kernel) every launch.
__device__ unsigned int g_cnt[NG * 32];

typedef __attribute__((ext_vector_type(8))) short short8;
typedef __attribute__((ext_vector_type(4))) float floatx4;

// Split fp32 v into bf16 hi + bf16 lo (residual), packed (hi<<16)|lo.
__device__ __forceinline__ unsigned int split_pack(float v) {
    unsigned int u  = __float_as_uint(v);
    unsigned int hb = u & 0xffff0000u;          // truncated-bf16 hi, exact in fp32
    float r = v - __uint_as_float(hb);          // exact residual
    return hb | (__float_as_uint(r) >> 16);
}

__device__ __forceinline__ float sigmoidf_(float z) {
    return 1.0f / (1.0f + __expf(-z));
}

__device__ __forceinline__ void unpack_pk(const unsigned int* hp, short8& ah, short8& al) {
    uint4 pa = *(const uint4*)(hp);
    uint4 pb = *(const uint4*)(hp + 4);
    unsigned int pv[8] = {pa.x, pa.y, pa.z, pa.w, pb.x, pb.y, pb.z, pb.w};
#pragma unroll
    for (int j = 0; j < 8; ++j) {
        ah[j] = (short)(pv[j] >> 16);
        al[j] = (short)(pv[j] & 0xffffu);
    }
}

__device__ __forceinline__ void cvt_x(const float* xp, short8& ah, short8& al) {
    float4 xa = *(const float4*)(xp);
    float4 xb = *(const float4*)(xp + 4);
    float xv[8] = {xa.x, xa.y, xa.z, xa.w, xb.x, xb.y, xb.z, xb.w};
#pragma unroll
    for (int j = 0; j < 8; ++j) {
        unsigned int u  = __float_as_uint(xv[j]);
        unsigned int hb = u & 0xffff0000u;
        float r = xv[j] - __uint_as_float(hb);
        ah[j] = (short)(u >> 16);
        al[j] = (short)(__float_as_uint(r) >> 16);
    }
}

// Group-local barrier: seq_cst agent-scope RMW arrival + seq_cst agent-scope
// spin loads (strongest device-coherent idiom; compiler emits the vmcnt drain,
// L2 writeback and invalidate). 12 arrivals per group. Monotonic counter.
__device__ __forceinline__ void gbar(unsigned int* cnt, unsigned int target) {
    __syncthreads();                   // all waves' stores drained before arrival
    if (threadIdx.x == 0) {
        __hip_atomic_fetch_add(cnt, 1u, __ATOMIC_SEQ_CST, __HIP_MEMORY_SCOPE_AGENT);
        while (__hip_atomic_load(cnt, __ATOMIC_SEQ_CST, __HIP_MEMORY_SCOPE_AGENT) < target) {}
    }
    __syncthreads();
}

// One LSTM layer role for one batch group (16 rows). Wave owns the group's
// m-tile x 2 column-tiles (8 units, all 4 gates). Weights pre-split to bf16
// hi/lo MFMA B-fragments in registers.
// MFMA 16x16x32_bf16: A: m=lane&15,k=quad*8+j ; D: col=lane&15, row=quad*4+r
template<int NKC, int KX, int GW, int UU, bool L1>
__device__ void lstm_role(const float* __restrict__ x,
                          const float* __restrict__ Wm, const float* __restrict__ Um,
                          const float* __restrict__ bias,
                          unsigned int* __restrict__ h1pk, unsigned int* __restrict__ h2pk,
                          float* __restrict__ out, unsigned int* __restrict__ cnt,
                          int m0, int wid, float (*zex)[17])
{
    const int lane = threadIdx.x & 63;
    const int n    = lane & 15;
    const int quad = lane >> 4;
    const int gate = n >> 2;
    const int u0   = wid * 8;             // 8 units per wave (2 coltiles x 4)
    const int arow = m0 + n;              // A-fragment row this lane loads
    const int b_l  = lane >> 2;           // epilogue: batch-local 0..15
    const int ul   = lane & 3;            // epilogue: unit-local 0..3

    // ---- one-time: weight B-fragments (hi/lo split), bias ----
    short8 bh[2][NKC], bl[2][NKC];
    float bias_v[2];
#pragma unroll
    for (int c = 0; c < 2; ++c) {
        const int col = gate * UU + u0 + c * 4 + (n & 3);
        bias_v[c] = bias[col];
#pragma unroll
        for (int kc = 0; kc < NKC; ++kc) {
#pragma unroll
            for (int j = 0; j < 8; ++j) {
                int k = kc * 32 + quad * 8 + j;
                float w = (k < KX) ? Wm[k * GW + col] : Um[(k - KX) * GW + col];
                unsigned int p = split_pack(w);
                bh[c][kc][j] = (short)(p >> 16);
                bl[c][kc][j] = (short)(p & 0xffffu);
            }
        }
    }

    // ---- zero the "step -1" h slice this wave owns (ws is poisoned) ----
#pragma unroll
    for (int c = 0; c < 2; ++c) {
        if (L1) h1pk[32768 + (m0 + b_l) * 256 + u0 + c * 4 + ul] = 0u;
        else    h2pk[16384 + (m0 + b_l) * 128 + u0 + c * 4 + ul] = 0u;
    }
    float cst[2] = {0.f, 0.f};

    // ---- init barrier: publishes the [-1]-slot zeros within the group ----
    gbar(cnt, GB * 1u);

    for (int it = 0; it <= 512; ++it) {
        const bool active = L1 ? (it < 512) : (it >= 1);
        if (active) {
            const int s = L1 ? it : (it - 1);
            floatx4 acc[2];
#pragma unroll
            for (int c = 0; c < 2; ++c)
                acc[c] = {bias_v[c], bias_v[c], bias_v[c], bias_v[c]};

            const float* xsrc = L1 ? (x + (size_t)arow * (512 * 64) + s * 64) : nullptr;
            const unsigned int* hA = L1
                ? (h1pk + ((it + 1) & 1) * 32768 + arow * 256)   // h1[s-1]
                : (h1pk + (s & 1) * 32768 + arow * 256);         // h1[s]
            const unsigned int* hB = L1
                ? nullptr
                : (h2pk + ((s + 1) & 1) * 16384 + arow * 128);   // h2[s-1]

#pragma unroll
            for (int kc = 0; kc < NKC; ++kc) {
                short8 ah, al;
                if (L1) {
                    if (kc < 2) cvt_x(xsrc + kc * 32 + quad * 8, ah, al);
                    else        unpack_pk(hA + (kc - 2) * 32 + quad * 8, ah, al);
                } else {
                    if (kc < 8) unpack_pk(hA + kc * 32 + quad * 8, ah, al);
                    else        unpack_pk(hB + (kc - 8) * 32 + quad * 8, ah, al);
                }
#pragma unroll
                for (int c = 0; c < 2; ++c) {
                    acc[c] = __builtin_amdgcn_mfma_f32_16x16x32_bf16(ah, bh[c][kc], acc[c], 0, 0, 0);
                    acc[c] = __builtin_amdgcn_mfma_f32_16x16x32_bf16(ah, bl[c][kc], acc[c], 0, 0, 0);
                    acc[c] = __builtin_amdgcn_mfma_f32_16x16x32_bf16(al, bh[c][kc], acc[c], 0, 0, 0);
                }
            }

            // ---- epilogue: per coltile, gate-gather via per-wave LDS tile.
            // Wave-level lgkmcnt(0) drains the ds_writes of ALL lanes of this
            // wave before any lane's read; memory clobber stops reordering. ----
#pragma unroll
            for (int c = 0; c < 2; ++c) {
#pragma unroll
                for (int r = 0; r < 4; ++r) zex[quad * 4 + r][n] = acc[c][r];
                asm volatile("s_waitcnt lgkmcnt(0)" ::: "memory");
                float zi = zex[b_l][ 0 + ul];
                float zf = zex[b_l][ 4 + ul];
                float zg = zex[b_l][ 8 + ul];
                float zo = zex[b_l][12 + ul];
                asm volatile("s_waitcnt lgkmcnt(0)" ::: "memory");
                float ig = sigmoidf_(zi);
                float fg = sigmoidf_(zf);
                float gg = fmaxf(zg, 0.f);
                float og = sigmoidf_(zo);
                cst[c] = fg * cst[c] + ig * gg;
                float h = og * fmaxf(cst[c], 0.f);
                unsigned int p = split_pack(h);
                int b = m0 + b_l;
                if (L1) {
                    h1pk[(it & 1) * 32768 + b * 256 + u0 + c * 4 + ul] = p;
                } else {
                    h2pk[(s & 1) * 16384 + b * 128 + u0 + c * 4 + ul] = p;
                    if (s == 511) out[b * 128 + u0 + c * 4 + ul] = h;
                }
            }
        }
        if (it < 512) gbar(cnt, GB * (unsigned)(it + 2));
    }
}

__global__ void __launch_bounds__(256, 1)
lstm_fused_kernel(const float* __restrict__ x,
                  const float* __restrict__ W1, const float* __restrict__ U1,
                  const float* __restrict__ b1,
                  const float* __restrict__ W2, const float* __restrict__ U2,
                  const float* __restrict__ b2,
                  float* __restrict__ out, unsigned int* __restrict__ ws)
{
    __shared__ float zex[4][16][17];       // per-wave gate-gather tiles
    unsigned int* h1pk = ws;               // [2][128][256] packed hi/lo bf16
    unsigned int* h2pk = ws + 65536;       // [2][128][128]
    const int g    = blockIdx.x & 7;       // batch group
    const int role = blockIdx.x >> 3;      // 0..7 layer1, 8..11 layer2
    const int wv   = threadIdx.x >> 6;
    const int m0   = g * 16;
    unsigned int* cnt = &g_cnt[g * 32];
    if (role < 8) {
        // layer1: 8 blocks x 4 waves = 32 unit-waves x 8 units = 256 units
        lstm_role<10, 64, 1024, 256, true >(x, W1, U1, b1, h1pk, h2pk, out, cnt,
                                            m0, role * 4 + wv, zex[wv]);
    } else {
        // layer2: 4 blocks x 4 waves = 16 unit-waves x 8 units = 128 units
        lstm_role<12, 256, 512, 128, false>(x, W2, U2, b2, h1pk, h2pk, out, cnt,
                                            m0, (role - 8) * 4 + wv, zex[wv]);
    }
}

// Pre-kernel (plain launch, cannot fail): zero barrier counters, write the
// diagnostic sentinel. Stream order publishes both to the main kernel.
// Signatures if main kernel fails: absmax~7 => main never ran (launch issue);
// absmax~0.162 => main ran but produced zeros (coherence issue).
__global__ void init_kernel(float* __restrict__ out) {
    int t = blockIdx.x * 256 + threadIdx.x;
    if (t < NG * 32) g_cnt[t] = 0u;
    if (t < 16384) out[t] = 7.0f;
}

extern "C" void kernel_launch(void* const* d_in, const int* in_sizes, int n_in,
                              void* d_out, int out_size, void* d_ws, size_t ws_size,
                              hipStream_t stream) {
    const float* x  = (const float*)d_in[0];
    const float* W1 = (const float*)d_in[1];
    const float* U1 = (const float*)d_in[2];
    const float* b1 = (const float*)d_in[3];
    const float* W2 = (const float*)d_in[4];
    const float* U2 = (const float*)d_in[5];
    const float* b2 = (const float*)d_in[6];
    float* out = (float*)d_out;
    unsigned int* ws = (unsigned int*)d_ws;
    init_kernel<<<64, 256, 0, stream>>>(out);
    lstm_fused_kernel<<<96, 256, 0, stream>>>(x, W1, U1, b1, W2, U2, b2, out, ws);
}